// Round 4
// baseline (586.662 us; speedup 1.0000x reference)
//
#include <hip/hip_runtime.h>
#include <math.h>

#define NV 50000
#define NM 150000   // 50000*3 rows

typedef float  f32x4  __attribute__((ext_vector_type(4)));
typedef __bf16 bf16x8 __attribute__((ext_vector_type(8)));
// 4-byte-aligned float4 (K=207 rows are only dword-aligned)
typedef float  f4u    __attribute__((ext_vector_type(4), aligned(4)));

// par[j] for j in 0..23 (par[0] unused); depth[j] = chain depth
__constant__ int c_par[24]   = {0, 0,0,0, 1,2,3, 4,5,6, 7,8,9,9,9, 12,13,14, 16,17, 18,19, 20,21};
__constant__ int c_depth[24] = {0, 1,1,1, 2,2,2, 3,3,3, 4,4,4,4,4, 5,5,5, 6,6, 7,7, 8,8};

// depth-4 A-chunk pipeline: 2 f4u per chunk, statically indexed (abuf[c&3])
#define LOAD_CHUNK(slot, cc) do {                                          \
    if ((cc) < NFULL) {                                                    \
        abuf[slot][0] = *(const f4u*)(Arow + (cc)*32 + kb*8);              \
        abuf[slot][1] = *(const f4u*)(Arow + (cc)*32 + kb*8 + 4);          \
    } else {                                                               \
        float tv[8];                                                       \
        _Pragma("unroll")                                                  \
        for (int e = 0; e < 8; ++e) {                                      \
            int kk = (cc)*32 + kb*8 + e;                                   \
            tv[e] = (kk < K) ? Arow[kk] : 0.f;                             \
        }                                                                  \
        abuf[slot][0] = (f4u){tv[0],tv[1],tv[2],tv[3]};                    \
        abuf[slot][1] = (f4u){tv[4],tv[5],tv[6],tv[7]};                    \
    }                                                                      \
} while (0)

// transpose beta [64][300] -> betaT [300][64]; zero J [64][24][3]
__global__ __launch_bounds__(256)
void prep_kernel(const float* __restrict__ beta, float* __restrict__ betaT,
                 float* __restrict__ J)
{
    int i = blockIdx.x * 256 + threadIdx.x;
    if (i < 300 * 64) {
        int k = i >> 6, b = i & 63;
        betaT[i] = beta[b * 300 + k];
    }
    if (i < 64 * 24 * 3) J[i] = 0.f;
}

// bf16-MFMA tall-skinny GEMM (MODE0 only now): C[row][b] = A.Bt + add[row].
// v4: depth-4 chunk rotation (32 VGPR in flight, fits the 128-VGPR cap without
// the serialization the v3 a[20] full-row issue provoked).
template<int K>
__global__ __launch_bounds__(512, 4)
void gemm_mfma(const float* __restrict__ A, const float* __restrict__ Bt,
               const float* __restrict__ add, float* __restrict__ C)
{
    constexpr int NFULL = K / 32;            // 9 (K=300)
    constexpr int NC    = NFULL + 1;         // 10
    constexpr int PB    = NC * 32 + 8;       // 328
    __shared__ __bf16 Bs[64 * PB];           // 41.0 KB

    const int t    = threadIdx.x;
    const int row0 = blockIdx.x * 128;
    const int w    = __builtin_amdgcn_readfirstlane(t >> 6);
    const int l    = t & 63;
    const int lr   = l & 15;
    const int kb   = l >> 4;

    // stage Bt[K][64] -> Bs[n][k] bf16 (coalesced loads, b128 writes)
    constexpr int NTASK = 64 * NC * 4;
    #pragma unroll
    for (int s = 0; s < (NTASK + 511) / 512; ++s) {
        const int id = t + s * 512;
        if (id < NTASK) {
            const int n  = id & 63;
            const int k8 = (id >> 6) * 8;
            bf16x8 bv;
            #pragma unroll
            for (int e = 0; e < 8; ++e) {
                int k = k8 + e;
                bv[e] = (__bf16)((k < K) ? Bt[(size_t)k * 64 + n] : 0.f);
            }
            *(bf16x8*)(Bs + n * PB + k8) = bv;
        }
    }
    __syncthreads();

    if (row0 + w * 16 >= NM) return;         // whole-wave (NM%16==0), after barrier
    const int grow = row0 + w * 16 + lr;
    const float* Arow = A + (size_t)grow * K;

    f4u abuf[4][2];
    #pragma unroll
    for (int d = 0; d < 4; ++d) LOAD_CHUNK(d, d);

    f32x4 acc[4] = {};
    #pragma unroll
    for (int c = 0; c < NC; ++c) {
        bf16x8 af;
        #pragma unroll
        for (int e = 0; e < 4; ++e) {
            af[e]     = (__bf16)abuf[c & 3][0][e];
            af[4 + e] = (__bf16)abuf[c & 3][1][e];
        }
        #pragma unroll
        for (int n = 0; n < 4; ++n) {
            const bf16x8 bfv = *(const bf16x8*)(Bs + (n * 16 + lr) * PB + c * 32 + kb * 8);
            acc[n] = __builtin_amdgcn_mfma_f32_16x16x32_bf16(af, bfv, acc[n], 0, 0, 0);
        }
        if (c + 4 < NC) LOAD_CHUNK(c & 3, c + 4);
    }

    // epilogue: D row = kb*4+r (local), col b = n*16+lr
    f4u ta = *(const f4u*)(add + row0 + w * 16 + kb * 4);
    #pragma unroll
    for (int n = 0; n < 4; ++n)
        #pragma unroll
        for (int r = 0; r < 4; ++r)
            C[(size_t)(row0 + w * 16 + kb * 4 + r) * 64 + n * 16 + lr] = acc[n][r] + ta[r];
}

// Fused gemm2 + skin: block = 126 NM-rows (42 whole vertices), computed as a
// 128-row MFMA tile (2-row overlap waste). Phase 1: v_posed -> LDS VP[128][67]
// (pitch 67: epilogue writes & skin reads <=2-way banks = free). Phase 2: wave w
// owns batch-group w (b = w*8+bi wave-uniform -> G' reads are s_loads); lanes
// 0..41 each own one vertex. Saves the 76.8 MB vp HBM round-trip.
__global__ __launch_bounds__(512, 4)
void posed_skin(const float* __restrict__ A, const float* __restrict__ Bt,
                const float* __restrict__ vs, const float* __restrict__ G,
                const float* __restrict__ wts, float* __restrict__ out)
{
    constexpr int K     = 207;
    constexpr int NFULL = K / 32;            // 6
    constexpr int NC    = NFULL + 1;         // 7
    constexpr int PB    = NC * 32 + 8;       // 232
    __shared__ __bf16 Bs[64 * PB];           // 29.7 KB
    __shared__ float  VP[128 * 67];          // 34.3 KB   (total 64.0 KB -> 2 blk/CU)

    const int t    = threadIdx.x;
    const int row0 = blockIdx.x * 126;       // vertex-aligned (126 = 42*3)
    const int w    = __builtin_amdgcn_readfirstlane(t >> 6);
    const int l    = t & 63;
    const int lr   = l & 15;
    const int kb   = l >> 4;

    // stage Bt (lrotT [207][64]) -> Bs
    constexpr int NTASK = 64 * NC * 4;
    #pragma unroll
    for (int s = 0; s < (NTASK + 511) / 512; ++s) {
        const int id = t + s * 512;
        if (id < NTASK) {
            const int n  = id & 63;
            const int k8 = (id >> 6) * 8;
            bf16x8 bv;
            #pragma unroll
            for (int e = 0; e < 8; ++e) {
                int k = k8 + e;
                bv[e] = (__bf16)((k < K) ? Bt[(size_t)k * 64 + n] : 0.f);
            }
            *(bf16x8*)(Bs + n * PB + k8) = bv;
        }
    }
    __syncthreads();

    // phase 1: MFMA, operands swapped (M=batch, N=rows). No early return (barrier
    // + skin follow); OOB rows clamped, their VP rows are never consumed.
    const int grow = row0 + w * 16 + lr;
    const int arow = grow < NM ? grow : NM - 1;
    const float* Arow = A + (size_t)arow * K;

    f4u abuf[4][2];
    #pragma unroll
    for (int d = 0; d < 4; ++d) LOAD_CHUNK(d, d);

    f32x4 acc[4] = {};
    #pragma unroll
    for (int c = 0; c < NC; ++c) {
        bf16x8 af;
        #pragma unroll
        for (int e = 0; e < 4; ++e) {
            af[e]     = (__bf16)abuf[c & 3][0][e];
            af[4 + e] = (__bf16)abuf[c & 3][1][e];
        }
        #pragma unroll
        for (int m = 0; m < 4; ++m) {
            const bf16x8 bfv = *(const bf16x8*)(Bs + (m * 16 + lr) * PB + c * 32 + kb * 8);
            acc[m] = __builtin_amdgcn_mfma_f32_16x16x32_bf16(bfv, af, acc[m], 0, 0, 0);
        }
        if (c + 4 < NC) LOAD_CHUNK(c & 3, c + 4);
    }

    // epilogue -> LDS: lane holds (b = m*16+kb*4+r, local row = w*16+lr)
    {
        const int lrow = w * 16 + lr;
        const float* av = vs + (size_t)arow * 64;
        #pragma unroll
        for (int m = 0; m < 4; ++m) {
            f4u a4 = *(const f4u*)(av + m * 16 + kb * 4);
            #pragma unroll
            for (int r = 0; r < 4; ++r)
                VP[lrow * 67 + m * 16 + kb * 4 + r] = acc[m][r] + a4[r];
        }
    }
    __syncthreads();

    // phase 2: skin. wave w <-> batches w*8..w*8+7; lane vl<42 <-> vertex.
    const int vl = l;
    if (vl < 42) {
        const int v = row0 / 3 + vl;
        if (v < NV) {
            float wj[24];
            const f4u* wp = (const f4u*)(wts + (size_t)v * 24);
            #pragma unroll
            for (int q = 0; q < 6; ++q) {
                f4u tw = wp[q];
                wj[q*4+0]=tw[0]; wj[q*4+1]=tw[1]; wj[q*4+2]=tw[2]; wj[q*4+3]=tw[3];
            }
            const float px_ = VP[(3*vl+0)*67 + 0];  // (touch nothing; indices below)
            (void)px_;
            #pragma unroll
            for (int bi = 0; bi < 8; ++bi) {
                const int b = w * 8 + bi;            // wave-uniform
                float px = VP[(3*vl+0)*67 + b];
                float py = VP[(3*vl+1)*67 + b];
                float pz = VP[(3*vl+2)*67 + b];
                float ox=0.f, oy=0.f, oz=0.f;
                const float* Gb = G + (size_t)b * 24 * 12;
                #pragma unroll
                for (int j = 0; j < 24; ++j) {
                    const float* g = Gb + j*12;      // uniform -> s_load
                    float wjj = wj[j];
                    ox += wjj * (g[0]*px + g[1]*py + g[2]*pz  + g[3]);
                    oy += wjj * (g[4]*px + g[5]*py + g[6]*pz  + g[7]);
                    oz += wjj * (g[8]*px + g[9]*py + g[10]*pz + g[11]);
                }
                float* ob = out + (size_t)b * NM + (size_t)v * 3;
                ob[0] = ox; ob[1] = oy; ob[2] = oz;
            }
        }
    }
}

// J[b][j][d] += sum_v Jr[j][v] * vs[v*3+d][b]   (vs is [NM][64])
__global__ __launch_bounds__(512)
void jreduce_kernel(const float* __restrict__ vs, const float* __restrict__ Jr,
                    float* J)
{
    __shared__ float Ls[4][64][73];     // 74.75 KB
    const int t = threadIdx.x;
    const int b = t & 63;
    const int w = __builtin_amdgcn_readfirstlane(t >> 6);

    float acc[24][3];
    #pragma unroll
    for (int j = 0; j < 24; ++j) { acc[j][0]=0.f; acc[j][1]=0.f; acc[j][2]=0.f; }

    const int v0 = blockIdx.x * 200 + w * 25;
    #pragma unroll 5
    for (int v = v0; v < v0 + 25; ++v) {
        float p0 = vs[(size_t)(v*3+0)*64 + b];
        float p1 = vs[(size_t)(v*3+1)*64 + b];
        float p2 = vs[(size_t)(v*3+2)*64 + b];
        #pragma unroll
        for (int j = 0; j < 24; ++j) {
            float r = Jr[(size_t)j*NV + v];
            acc[j][0] += r*p0; acc[j][1] += r*p1; acc[j][2] += r*p2;
        }
    }

    if (w < 4) {
        float* d = Ls[w][b];
        #pragma unroll
        for (int j = 0; j < 24; ++j) {
            d[j*3+0] = acc[j][0]; d[j*3+1] = acc[j][1]; d[j*3+2] = acc[j][2];
        }
    }
    __syncthreads();
    if (w >= 4) {
        float* d = Ls[w-4][b];
        #pragma unroll
        for (int j = 0; j < 24; ++j) {
            d[j*3+0] += acc[j][0]; d[j*3+1] += acc[j][1]; d[j*3+2] += acc[j][2];
        }
    }
    __syncthreads();

    #pragma unroll
    for (int q = 0; q < 9; ++q) {
        int oid = t * 9 + q;
        int bb = oid / 72, c = oid - bb * 72;
        float s = Ls[0][bb][c] + Ls[1][bb][c] + Ls[2][bb][c] + Ls[3][bb][c];
        atomicAdd(&J[(size_t)bb * 72 + c], s);
    }
}

// per-(b,j): rodrigues -> R; lrotT [207][64]; level-parallel kinematic chain; G' [64][24][12]
__global__ __launch_bounds__(192)
void pose_kernel(const float* __restrict__ pose, const float* __restrict__ J,
                 float* __restrict__ G, float* __restrict__ lrotT)
{
    __shared__ float Gl[8][24][12];
    __shared__ float Gc[8][24][12];
    const int t  = threadIdx.x;
    const int bl = t / 24;
    const int j  = t % 24;
    const int b  = blockIdx.x * 8 + bl;

    float tx = pose[b*72 + j*3 + 0];
    float ty = pose[b*72 + j*3 + 1];
    float tz = pose[b*72 + j*3 + 2];
    float ax = tx + 1e-8f, ay = ty + 1e-8f, az = tz + 1e-8f;
    float angle = sqrtf(ax*ax + ay*ay + az*az);
    float nx = tx / angle, ny = ty / angle, nz = tz / angle;
    float half = 0.5f * angle;
    float sw = sinf(half);
    float qw = cosf(half), qx = sw*nx, qy = sw*ny, qz = sw*nz;
    float qn = sqrtf(qw*qw + qx*qx + qy*qy + qz*qz);
    qw /= qn; qx /= qn; qy /= qn; qz /= qn;
    float w2=qw*qw, x2=qx*qx, y2=qy*qy, z2=qz*qz;
    float xy=qx*qy, xz=qx*qz, yz=qy*qz, wx=qw*qx, wy=qw*qy, wz=qw*qz;
    float r00 = w2+x2-y2-z2, r01 = 2.f*(xy-wz), r02 = 2.f*(wy+xz);
    float r10 = 2.f*(wz+xy), r11 = w2-x2+y2-z2, r12 = 2.f*(yz-wx);
    float r20 = 2.f*(xz-wy), r21 = 2.f*(wx+yz), r22 = w2-x2-y2+z2;

    if (j >= 1) {
        const int k9 = (j-1)*9;
        lrotT[(size_t)(k9+0)*64+b]=r00-1.f; lrotT[(size_t)(k9+1)*64+b]=r01;
        lrotT[(size_t)(k9+2)*64+b]=r02;     lrotT[(size_t)(k9+3)*64+b]=r10;
        lrotT[(size_t)(k9+4)*64+b]=r11-1.f; lrotT[(size_t)(k9+5)*64+b]=r12;
        lrotT[(size_t)(k9+6)*64+b]=r20;     lrotT[(size_t)(k9+7)*64+b]=r21;
        lrotT[(size_t)(k9+8)*64+b]=r22-1.f;
    }
    float jx = J[(size_t)(b*24+j)*3+0];
    float jy = J[(size_t)(b*24+j)*3+1];
    float jz = J[(size_t)(b*24+j)*3+2];
    float rx = jx, ry = jy, rz = jz;
    if (j > 0) {
        int p = c_par[j];
        rx -= J[(size_t)(b*24+p)*3+0];
        ry -= J[(size_t)(b*24+p)*3+1];
        rz -= J[(size_t)(b*24+p)*3+2];
    }
    float* gl = Gl[bl][j];
    gl[0]=r00; gl[1]=r01; gl[2]=r02;  gl[3]=rx;
    gl[4]=r10; gl[5]=r11; gl[6]=r12;  gl[7]=ry;
    gl[8]=r20; gl[9]=r21; gl[10]=r22; gl[11]=rz;
    __syncthreads();

    if (j == 0) {
        #pragma unroll
        for (int c = 0; c < 12; ++c) Gc[bl][0][c] = Gl[bl][0][c];
    }
    const int dj = c_depth[j];
    for (int lvl = 1; lvl <= 8; ++lvl) {
        __syncthreads();
        if (dj == lvl) {
            const float* Aa = Gc[bl][c_par[j]];
            const float* Bb = Gl[bl][j];
            float* D = Gc[bl][j];
            #pragma unroll
            for (int r = 0; r < 3; ++r) {
                float a0=Aa[r*4+0], a1=Aa[r*4+1], a2=Aa[r*4+2], a3=Aa[r*4+3];
                D[r*4+0] = a0*Bb[0] + a1*Bb[4] + a2*Bb[8];
                D[r*4+1] = a0*Bb[1] + a1*Bb[5] + a2*Bb[9];
                D[r*4+2] = a0*Bb[2] + a1*Bb[6] + a2*Bb[10];
                D[r*4+3] = a0*Bb[3] + a1*Bb[7] + a2*Bb[11] + a3;
            }
        }
    }
    __syncthreads();

    const float* Gi = Gc[bl][j];
    float* go = G + (size_t)(b*24 + j) * 12;
    #pragma unroll
    for (int r = 0; r < 3; ++r) {
        go[r*4+0] = Gi[r*4+0];
        go[r*4+1] = Gi[r*4+1];
        go[r*4+2] = Gi[r*4+2];
        go[r*4+3] = Gi[r*4+3] - (Gi[r*4+0]*jx + Gi[r*4+1]*jy + Gi[r*4+2]*jz);
    }
}

extern "C" void kernel_launch(void* const* d_in, const int* in_sizes, int n_in,
                              void* d_out, int out_size, void* d_ws, size_t ws_size,
                              hipStream_t stream) {
    const float* pose       = (const float*)d_in[0];
    const float* beta       = (const float*)d_in[1];
    const float* v_template = (const float*)d_in[2];
    const float* shapedirs  = (const float*)d_in[3];
    const float* posedirs   = (const float*)d_in[4];
    const float* Jreg       = (const float*)d_in[5];
    const float* weights    = (const float*)d_in[6];
    float* out = (float*)d_out;

    char* ws = (char*)d_ws;
    float* vs_ws    = (float*)(ws);                 // [NM][64]  38.4 MB
    float* betaT_ws = (float*)(ws + 38400000);      // [300][64] (dead after gemm1)
    float* J_ws     = (float*)(ws + 76800000);      // [64][24][3]
    float* G_ws     = (float*)(ws + 76818432);      // [64][24][12]
    float* lrotT_ws = (float*)(ws + 76892160);      // [207][64]

    prep_kernel<<<75, 256, 0, stream>>>(beta, betaT_ws, J_ws);
    gemm_mfma<300><<<1172, 512, 0, stream>>>(shapedirs, betaT_ws, v_template, vs_ws);
    jreduce_kernel<<<250, 512, 0, stream>>>(vs_ws, Jreg, J_ws);
    pose_kernel<<<8, 192, 0, stream>>>(pose, J_ws, G_ws, lrotT_ws);
    posed_skin<<<1191, 512, 0, stream>>>(posedirs, lrotT_ws, vs_ws, G_ws, weights, out);
}